// Round 3
// baseline (83.870 us; speedup 1.0000x reference)
//
#include <hip/hip_runtime.h>
#include <math.h>

// Problem constants (from reference)
#define XS 540
#define YS 540
#define NB 4            // batch
#define NBOX 64
#define TILE 36         // 36x36 cells per block
#define TPX 15          // 540 / 36
#define NTILE (TPX * TPX)       // 225
#define NSLOT (NB * NTILE)      // 900
#define CELLS_PER_TILE (TILE * TILE)

// d_ws layout: uint slot[NSLOT][4] = { s1(f32), s2(f32), cnt(f32), flag(u32) }
// flag semantics: ==1u means "this slot's partials are published".
// Harness poisons ws to 0xAAAAAAAA before every launch, so flags start != 1.
// No init pass needed -> single kernel node.

#define FLAG_SET 1u

__global__ __launch_bounds__(256) void hmdl_fused(
    const float* __restrict__ logits,   // [4,1,540,540]
    const float* __restrict__ boxes,    // [4,64,7]
    const float* __restrict__ hmaps,    // [4,1,540,540]
    float* __restrict__ ws,             // NSLOT*4 floats (flag word aliased as uint)
    float* __restrict__ out)
{
    __shared__ float s_cx[NBOX], s_cy[NBOX], s_c[NBOX], s_s[NBOX];
    __shared__ float s_hw[NBOX], s_hl[NBOX], s_hv[NBOX];
    __shared__ int   s_sel[NBOX];
    __shared__ int   s_nsel;
    __shared__ float s_red[3][4];
    __shared__ float s_comb[NB], s_has[NB];

    const int b    = blockIdx.y;
    const int tile = blockIdx.x;
    const int tx0  = (tile % TPX) * TILE;
    const int ty0  = (tile / TPX) * TILE;
    const int tid  = threadIdx.x;

    // ---- per-box constants + tile culling (wave 0 only; order-preserving compact) ----
    if (tid < NBOX) {
        const float* bx = boxes + (b * NBOX + tid) * 7;
        float b0 = bx[0], b1 = bx[1], b3 = bx[3], b4 = bx[4], b5 = bx[5], b6 = bx[6];
        float cx = (b0 - (-54.0f)) / 0.2f;
        float cy = (b1 - (-54.0f)) / 0.2f;
        float hw = (b3 / 0.2f) * 0.5f;
        float hl = (b4 / 0.2f) * 0.5f;
        float c  = cosf(-b6);
        float s  = sinf(-b6);
        float hv = b5 / 5.0f;   // h / (PC_RANGE[5] + 2.0) = h / 5
        s_cx[tid] = cx; s_cy[tid] = cy; s_c[tid] = c; s_s[tid] = s;
        s_hw[tid] = hw; s_hl[tid] = hl; s_hv[tid] = hv;

        // exact AABB of the rotated rect
        float ex = fabsf(hw * c) + fabsf(hl * s);
        float ey = fabsf(hw * s) + fabsf(hl * c);
        bool hit = (cx + ex >= (float)tx0) && (cx - ex <= (float)(tx0 + TILE - 1)) &&
                   (cy + ey >= (float)ty0) && (cy - ey <= (float)(ty0 + TILE - 1));
        unsigned long long m = __ballot(hit);
        if (hit) {
            int pos = __popcll(m & ((1ull << tid) - 1ull));
            s_sel[pos] = tid;   // ascending j order preserved -> "last box wins" intact
        }
        if (tid == 0) s_nsel = __popcll(m);
    }
    __syncthreads();
    const int nsel = s_nsel;

    float a1 = 0.0f, a2 = 0.0f, ac = 0.0f;

    for (int i = tid; i < CELLS_PER_TILE; i += 256) {
        const int x = tx0 + (i % TILE);
        const int y = ty0 + (i / TILE);
        const float xg = (float)x, yg = (float)y;

        // rasterize: last covering box wins
        float gt = 0.0f;
        for (int k = 0; k < nsel; ++k) {
            const int j = s_sel[k];
            float dx = xg - s_cx[j];
            float dy = yg - s_cy[j];
            float lx = dx * s_c[j] - dy * s_s[j];
            float ly = dx * s_s[j] + dy * s_c[j];
            if (fabsf(lx) <= s_hw[j] && fabsf(ly) <= s_hl[j]) gt = s_hv[j];
        }

        const int idx = (b * YS + y) * XS + x;
        const float xv = logits[idx];
        const float hm = hmaps[idx];

        const bool pos = gt > 0.0f;                 // neg == !pos (gt is 0 or hv>0)
        const float weight = pos ? 5.0f : 0.1f;
        const bool point = hm > 0.0f;
        const float valid = (pos || point) ? 1.0f : 0.0f;   // pos | (neg & point)

        // One transcendental pair per cell:
        //   t = e^{-|x|};  sigmoid(x) = x>=0 ? 1/(1+t) : t/(1+t)
        const float t  = __expf(-fabsf(xv));
        const float bce = fmaxf(xv, 0.0f) - xv * gt + __logf(1.0f + t);
        const float r  = 1.0f / (1.0f + t);
        const float p  = (xv >= 0.0f) ? r : (t * r);
        const float pt = p * gt + (1.0f - p) * (1.0f - gt);
        const float aw = 0.25f * gt + 0.75f * (1.0f - gt);
        const float om = 1.0f - pt;
        const float fw = om * om * aw * weight;

        a1 += weight * bce * valid;
        a2 += fw * bce * valid;
        ac += valid;
    }

    // ---- block reduction: wave64 shuffle + cross-wave LDS ----
    for (int off = 32; off > 0; off >>= 1) {
        a1 += __shfl_down(a1, off);
        a2 += __shfl_down(a2, off);
        ac += __shfl_down(ac, off);
    }
    const int wave = tid >> 6;
    if ((tid & 63) == 0) { s_red[0][wave] = a1; s_red[1][wave] = a2; s_red[2][wave] = ac; }
    __syncthreads();

    const int slot = b * NTILE + tile;
    if (tid == 0) {
        float t1 = s_red[0][0] + s_red[0][1] + s_red[0][2] + s_red[0][3];
        float t2 = s_red[1][0] + s_red[1][1] + s_red[1][2] + s_red[1][3];
        float t3 = s_red[2][0] + s_red[2][1] + s_red[2][2] + s_red[2][3];
        float* sp = ws + slot * 4;
        __hip_atomic_store(&sp[0], t1, __ATOMIC_RELAXED, __HIP_MEMORY_SCOPE_AGENT);
        __hip_atomic_store(&sp[1], t2, __ATOMIC_RELAXED, __HIP_MEMORY_SCOPE_AGENT);
        __hip_atomic_store(&sp[2], t3, __ATOMIC_RELAXED, __HIP_MEMORY_SCOPE_AGENT);
        __hip_atomic_store((unsigned int*)&sp[3], FLAG_SET,
                           __ATOMIC_RELEASE, __HIP_MEMORY_SCOPE_AGENT);
    }

    // ---- finalize: block (0,0) only; wave w reduces sample w's 225 slots ----
    if (tile != 0 || b != 0) return;

    const int lane = tid & 63;
    const int bs   = wave;              // sample this wave owns (4 waves, 4 samples)

    double d1 = 0.0, d2 = 0.0, d3 = 0.0;
    for (int t = lane; t < NTILE; t += 64) {
        float* sp = ws + (bs * NTILE + t) * 4;
        // spin until published (agent-scope acquire); flags start as 0xAAAAAAAA poison
        while (__hip_atomic_load((unsigned int*)&sp[3],
                                 __ATOMIC_ACQUIRE, __HIP_MEMORY_SCOPE_AGENT) != FLAG_SET) {
            __builtin_amdgcn_s_sleep(2);
        }
        d1 += (double)__hip_atomic_load(&sp[0], __ATOMIC_RELAXED, __HIP_MEMORY_SCOPE_AGENT);
        d2 += (double)__hip_atomic_load(&sp[1], __ATOMIC_RELAXED, __HIP_MEMORY_SCOPE_AGENT);
        d3 += (double)__hip_atomic_load(&sp[2], __ATOMIC_RELAXED, __HIP_MEMORY_SCOPE_AGENT);
    }
    for (int off = 32; off > 0; off >>= 1) {
        d1 += __shfl_down(d1, off);
        d2 += __shfl_down(d2, off);
        d3 += __shfl_down(d3, off);
    }
    if (lane == 0) {
        float cnt   = (float)d3;
        float denom = fmaxf(cnt, 1.0f);
        float bl = (float)d1 / denom;
        float fl = (float)d2 / denom;
        bool has = cnt > 0.0f;
        s_comb[bs] = has ? (0.5f * bl + 0.5f * fl) : 0.0f;
        s_has[bs]  = has ? 1.0f : 0.0f;
    }
    __syncthreads();
    if (tid == 0) {
        float total = s_comb[0] + s_comb[1] + s_comb[2] + s_comb[3];
        float ns    = s_has[0] + s_has[1] + s_has[2] + s_has[3];
        out[0] = (ns > 0.0f) ? (total / fmaxf(ns, 1.0f)) : total;
    }
}

extern "C" void kernel_launch(void* const* d_in, const int* in_sizes, int n_in,
                              void* d_out, int out_size, void* d_ws, size_t ws_size,
                              hipStream_t stream) {
    const float* logits = (const float*)d_in[0];
    const float* boxes  = (const float*)d_in[1];
    const float* hmaps  = (const float*)d_in[2];
    float* out = (float*)d_out;
    float* ws  = (float*)d_ws;

    dim3 grid(NTILE, NB);
    hmdl_fused<<<grid, 256, 0, stream>>>(logits, boxes, hmaps, ws, out);
}

// Round 4
// 68.341 us; speedup vs baseline: 1.2272x; 1.2272x over previous
//
#include <hip/hip_runtime.h>
#include <math.h>

// Problem constants (from reference)
#define XS 540
#define YS 540
#define NB 4            // batch
#define NBOX 64
#define TILE 36         // 36x36 cells per block
#define TPX 15          // 540 / 36
#define NTILE (TPX * TPX)       // 225
#define Q_PER_TILE (36 * 9)     // 324 float4 groups per tile
#define XS4 (XS / 4)            // 135 float4 per row

// d_ws layout: float part[NB][NTILE][4] = { s1, s2, cnt, pad }.
// Every slot fully written by its owning block -> no zero-init needed.

__global__ __launch_bounds__(256) void hmdl_main(
    const float* __restrict__ logits,   // [4,1,540,540]
    const float* __restrict__ boxes,    // [4,64,7]
    const float* __restrict__ hmaps,    // [4,1,540,540]
    float4* __restrict__ part)          // [NB*NTILE]
{
    __shared__ float s_cx[NBOX], s_cy[NBOX], s_c[NBOX], s_s[NBOX];
    __shared__ float s_hw[NBOX], s_hl[NBOX], s_hv[NBOX];
    __shared__ int   s_sel[NBOX];
    __shared__ int   s_nsel;
    __shared__ float s_red[3][4];

    const int b    = blockIdx.y;
    const int tile = blockIdx.x;
    const int tx0  = (tile % TPX) * TILE;
    const int ty0  = (tile / TPX) * TILE;
    const int tid  = threadIdx.x;

    // ---- per-box constants + tile culling (wave 0 only; order-preserving compact) ----
    if (tid < NBOX) {
        const float* bx = boxes + (b * NBOX + tid) * 7;
        float b0 = bx[0], b1 = bx[1], b3 = bx[3], b4 = bx[4], b5 = bx[5], b6 = bx[6];
        float cx = (b0 - (-54.0f)) / 0.2f;
        float cy = (b1 - (-54.0f)) / 0.2f;
        float hw = (b3 / 0.2f) * 0.5f;
        float hl = (b4 / 0.2f) * 0.5f;
        float c  = cosf(-b6);
        float s  = sinf(-b6);
        float hv = b5 / 5.0f;   // h / (PC_RANGE[5] + 2.0) = h / 5
        s_cx[tid] = cx; s_cy[tid] = cy; s_c[tid] = c; s_s[tid] = s;
        s_hw[tid] = hw; s_hl[tid] = hl; s_hv[tid] = hv;

        // exact AABB of the rotated rect
        float ex = fabsf(hw * c) + fabsf(hl * s);
        float ey = fabsf(hw * s) + fabsf(hl * c);
        bool hit = (cx + ex >= (float)tx0) && (cx - ex <= (float)(tx0 + TILE - 1)) &&
                   (cy + ey >= (float)ty0) && (cy - ey <= (float)(ty0 + TILE - 1));
        unsigned long long m = __ballot(hit);
        if (hit) {
            int pos = __popcll(m & ((1ull << tid) - 1ull));
            s_sel[pos] = tid;   // ascending j order preserved -> "last box wins" intact
        }
        if (tid == 0) s_nsel = __popcll(m);
    }
    __syncthreads();
    const int nsel = s_nsel;

    const float4* lg4 = (const float4*)logits;
    const float4* hm4 = (const float4*)hmaps;

    float a1 = 0.0f, a2 = 0.0f, ac = 0.0f;

    for (int q = tid; q < Q_PER_TILE; q += 256) {
        const int row = q / 9;          // 0..35
        const int c4  = q - row * 9;    // 0..8
        const int y   = ty0 + row;
        const int x   = tx0 + c4 * 4;
        const float xg = (float)x, yg = (float)y;

        const int idx4 = (b * YS + y) * XS4 + (tx0 >> 2) + c4;
        const float4 xv = lg4[idx4];
        const float4 hm = hm4[idx4];

        // rasterize 4 consecutive cells: last covering box wins; incremental lx/ly
        float g0 = 0.0f, g1 = 0.0f, g2 = 0.0f, g3 = 0.0f;
        for (int k = 0; k < nsel; ++k) {
            const int j = s_sel[k];
            const float cj = s_c[j], sj = s_s[j];
            const float hw = s_hw[j], hl = s_hl[j], hv = s_hv[j];
            const float dx = xg - s_cx[j];
            const float dy = yg - s_cy[j];
            float lx = dx * cj - dy * sj;
            float ly = dx * sj + dy * cj;
            if (fabsf(lx) <= hw && fabsf(ly) <= hl) g0 = hv;
            lx += cj; ly += sj;
            if (fabsf(lx) <= hw && fabsf(ly) <= hl) g1 = hv;
            lx += cj; ly += sj;
            if (fabsf(lx) <= hw && fabsf(ly) <= hl) g2 = hv;
            lx += cj; ly += sj;
            if (fabsf(lx) <= hw && fabsf(ly) <= hl) g3 = hv;
        }

        const float gts[4] = { g0, g1, g2, g3 };
        const float xvs[4] = { xv.x, xv.y, xv.z, xv.w };
        const float hms[4] = { hm.x, hm.y, hm.z, hm.w };

        #pragma unroll
        for (int m = 0; m < 4; ++m) {
            const float gt = gts[m];
            const float x_ = xvs[m];
            const bool  pos = gt > 0.0f;                 // neg == !pos
            const float weight = pos ? 5.0f : 0.1f;
            const bool  point = hms[m] > 0.0f;
            const float valid = (pos || point) ? 1.0f : 0.0f;

            // t = e^{-|x|};  sigmoid(x) = x>=0 ? 1/(1+t) : t/(1+t)
            const float t  = __expf(-fabsf(x_));
            const float bce = fmaxf(x_, 0.0f) - x_ * gt + __logf(1.0f + t);
            const float r  = 1.0f / (1.0f + t);
            const float p  = (x_ >= 0.0f) ? r : (t * r);
            const float pt = p * gt + (1.0f - p) * (1.0f - gt);
            const float aw = 0.25f * gt + 0.75f * (1.0f - gt);
            const float om = 1.0f - pt;
            const float fw = om * om * aw * weight;

            a1 += weight * bce * valid;
            a2 += fw * bce * valid;
            ac += valid;
        }
    }

    // ---- block reduction: wave64 shuffle + cross-wave LDS ----
    for (int off = 32; off > 0; off >>= 1) {
        a1 += __shfl_down(a1, off);
        a2 += __shfl_down(a2, off);
        ac += __shfl_down(ac, off);
    }
    const int wave = tid >> 6;
    if ((tid & 63) == 0) { s_red[0][wave] = a1; s_red[1][wave] = a2; s_red[2][wave] = ac; }
    __syncthreads();
    if (tid == 0) {
        float t1 = s_red[0][0] + s_red[0][1] + s_red[0][2] + s_red[0][3];
        float t2 = s_red[1][0] + s_red[1][1] + s_red[1][2] + s_red[1][3];
        float t3 = s_red[2][0] + s_red[2][1] + s_red[2][2] + s_red[2][3];
        part[b * NTILE + tile] = make_float4(t1, t2, t3, 0.0f);
    }
}

// One block, 256 threads: wave w reduces sample w's 225 tile-partials.
__global__ __launch_bounds__(256) void hmdl_finalize(
    const float4* __restrict__ part, float* __restrict__ out)
{
    __shared__ float s_comb[NB];
    __shared__ float s_has[NB];

    const int tid  = threadIdx.x;
    const int b    = tid >> 6;
    const int lane = tid & 63;

    double d1 = 0.0, d2 = 0.0, d3 = 0.0;
    for (int t = lane; t < NTILE; t += 64) {
        float4 v = part[b * NTILE + t];
        d1 += (double)v.x; d2 += (double)v.y; d3 += (double)v.z;
    }
    for (int off = 32; off > 0; off >>= 1) {
        d1 += __shfl_down(d1, off);
        d2 += __shfl_down(d2, off);
        d3 += __shfl_down(d3, off);
    }
    if (lane == 0) {
        float cnt   = (float)d3;
        float denom = fmaxf(cnt, 1.0f);
        float bl = (float)d1 / denom;
        float fl = (float)d2 / denom;
        bool has = cnt > 0.0f;
        s_comb[b] = has ? (0.5f * bl + 0.5f * fl) : 0.0f;
        s_has[b]  = has ? 1.0f : 0.0f;
    }
    __syncthreads();
    if (tid == 0) {
        float total = s_comb[0] + s_comb[1] + s_comb[2] + s_comb[3];
        float ns    = s_has[0] + s_has[1] + s_has[2] + s_has[3];
        out[0] = (ns > 0.0f) ? (total / fmaxf(ns, 1.0f)) : total;
    }
}

extern "C" void kernel_launch(void* const* d_in, const int* in_sizes, int n_in,
                              void* d_out, int out_size, void* d_ws, size_t ws_size,
                              hipStream_t stream) {
    const float* logits = (const float*)d_in[0];
    const float* boxes  = (const float*)d_in[1];
    const float* hmaps  = (const float*)d_in[2];
    float* out = (float*)d_out;
    float4* part = (float4*)d_ws;

    dim3 grid(NTILE, NB);
    hmdl_main<<<grid, 256, 0, stream>>>(logits, boxes, hmaps, part);
    hmdl_finalize<<<1, 256, 0, stream>>>(part, out);
}